// Round 1
// baseline (629.398 us; speedup 1.0000x reference)
//
#include <hip/hip_runtime.h>
#include <cstddef>
#include <cstdint>

#define TIME_N 262144
#define BATCH  32
#define KW     1024
#define ST     256
#define CUTN   513
#define TCN    1026
#define FN     1029   // frames
#define FPAD   1152
#define CPAD   1152
#define XLEN   (FPAD * ST + KW)   // 295936 bf16 per batch row
#define XBLK   (XLEN / 256)       // 1156

// mask GEMM dims
#define MROWS  (BATCH * FN)   // 32928
#define MP     33024          // 258*128
#define KPH    544            // 513 -> 17*32
#define NPH    640            // 513 -> 5*128
// convT GEMM dims / flat bf16 t layout (re/im PAIR-INTERLEAVED: col 2y=re_y, 2y+1=im_y)
#define TBP    1032           // flat bf16 t row stride (16B-aligned)
#define FLATB  (FN * TBP)     // per-batch flat size
#define KPC    4128           // 4*1032, 129*32

// k_prep block ranges
#define PB_XPAD  (XBLK * BATCH)            // 36992
#define PB_WBF   (PB_XPAD + CPAD)          // +1152
#define PB_WLIN  (PB_WBF + NPH)            // +640
#define PB_TOTAL (PB_WLIN + KPC)           // +4128

// ---- k_conv1m 256^2 8-phase geometry ----
#define C1_BM   256
#define C1_BN   256
#define C1_BK   64
#define C1_NT   (KW / C1_BK)            // 16 K-tiles
#define C1_MB   129                     // ceil(32928/256)
#define C1_NB   5                       // 1280 cols
#define C1_BUF  65536                   // one dbuf: A 32KB + B 32KB

typedef __bf16 bf16x8 __attribute__((ext_vector_type(8)));
typedef float floatx4 __attribute__((ext_vector_type(4)));

__device__ __forceinline__ unsigned short f2bf(float f) {
    union { float f; unsigned u; } v; v.f = f;
    unsigned r = (v.u + 0x7fffu + ((v.u >> 16) & 1u)) >> 16;
    return (unsigned short)r;
}
__device__ __forceinline__ float bf2f(unsigned short s) {
    union { unsigned u; float f; } v; v.u = ((unsigned)s) << 16;
    return v.f;
}
// interleaved column n -> original channel index
__device__ __forceinline__ int permch(int n) {
    return (n & 1) ? (CUTN + (n >> 1)) : (n >> 1);
}

__device__ __forceinline__ void load_lds16(const void* g, void* l) {
    __builtin_amdgcn_global_load_lds(
        (const __attribute__((address_space(1))) void*)g,
        (__attribute__((address_space(3))) void*)l, 16, 0, 0);
}

// ---------------------------------------------------------------------------
// k_prep: all input-conversion work in ONE launch, split by blockIdx range.
// ---------------------------------------------------------------------------
__global__ __launch_bounds__(256) void k_prep(
    const float* __restrict__ x, const float* __restrict__ c1w,
    const float* __restrict__ lw, const float* __restrict__ wct,
    unsigned short* __restrict__ xb, unsigned short* __restrict__ wbf,
    unsigned short* __restrict__ wlb, unsigned short* __restrict__ wdb)
{
    const int bid = blockIdx.x;
    if (bid < PB_XPAD) {
        const int b = bid / XBLK;
        const int p = (bid - b * XBLK) * 256 + threadIdx.x;
        const int g = p - KW;
        float v = (g >= 0 && g < TIME_N) ? x[(size_t)b * TIME_N + g] : 0.0f;
        xb[(size_t)b * XLEN + p] = f2bf(v);
    } else if (bid < PB_WBF) {
        const int n = bid - PB_XPAD;              // 0..1151 interleaved row
        const int ch = (n < TCN) ? permch(n) : 0;
        for (int k = threadIdx.x; k < KW; k += 256) {
            float v = (n < TCN) ? c1w[(size_t)ch * KW + k] : 0.0f;
            wbf[(size_t)n * KW + k] = f2bf(v);
        }
    } else if (bid < PB_WLIN) {
        const int n = bid - PB_WBF;               // 0..639
        for (int k = threadIdx.x; k < KPH; k += 256) {
            float v = (n < CUTN && k < CUTN) ? lw[(size_t)n * CUTN + k] : 0.0f;
            wlb[(size_t)n * KPH + k] = f2bf(v);
        }
    } else {
        const int k = bid - PB_WLIN;              // 0..4127
        const int r = threadIdx.x;                // 0..255
        const int j = k / TBP;
        const int n = k - j * TBP;
        float v = 0.0f;
        if (n < TCN) {
            const int ch = permch(n);
            const int widx = (3 - j) * 256 + r;
            v = wct[(size_t)(2 * ch) * KW + widx] -
                wct[(size_t)(2 * ch + 1) * KW + widx];
        }
        wdb[(size_t)r * KPC + k] = f2bf(v);
    }
}

// ---------------------------------------------------------------------------
// k_conv1m: conv1 bf16 GEMM, 256x256 tile, BK=64, 8 waves (2Mx4N), dbuf'd
// LDS with 4-phase/K-tile interleave, counted-latency staging (all 8
// global_load_lds for tile t+1 issue in phase 1 of tile t; only drain is the
// tile-boundary __syncthreads, ~3 MFMA-phases after issue). LDS XOR-swizzle
// byte^=((row&7)<<4) realized via pre-swizzled GLOBAL source addresses
// (linear global_load_lds dest) + swizzled ds_read addresses.
// M is flattened across batches: row m -> (b = m/FN, f = m%FN).
// Epilogue: tanh(gamma*.) -> pair-interleaved tb2 + h=MLP(re,im), both-lane
// scheme (even lane owns frame fa, odd lane frame fa+1).
// ---------------------------------------------------------------------------
__global__ __launch_bounds__(512, 2) void k_conv1m(
    const unsigned short* __restrict__ xb, const unsigned short* __restrict__ wb,
    const float* __restrict__ gamma,
    const float* __restrict__ c1w, const float* __restrict__ c1b,
    const float* __restrict__ c2w, const float* __restrict__ c2b,
    unsigned short* __restrict__ tb2, unsigned short* __restrict__ h)
{
    extern __shared__ char lds[];              // 2 * C1_BUF bytes
    const int m0 = blockIdx.x * C1_BM;
    const int n0 = blockIdx.y * C1_BN;
    const int tid = threadIdx.x;
    const int wv = tid >> 6, lane = tid & 63;
    const int lm = lane & 15, lq = lane >> 4;
    const int wr = wv >> 2, wc = wv & 3;       // 2 x 4 wave grid

    // ---- staging: 8 x 1KB wave-chunks per thread-wave per K-tile ----
    // buf layout: [A.h0 16K][A.h1 16K][B.h0 16K][B.h1 16K]
    const unsigned short* src[8];
    int ldsq[8];
#pragma unroll
    for (int i = 0; i < 8; ++i) {
        const int c = wv * 8 + i;
        const int q = c * 1024 + lane * 16;    // linear byte offset in buf
        ldsq[i] = q;
        const int sec = q >> 14;               // 0..3 (16KB sections)
        const int p = q & 16383;
        const int row = p >> 7;                // 0..127 within section
        const int cb = (p & 127) ^ ((row & 7) << 4);   // inverse-swizzled col
        const int e = cb >> 1;                 // bf16 element 0..63
        if (sec < 2) {
            int m = m0 + sec * 128 + row;
            if (m >= MROWS) m = 0;             // clamp; epilogue guards store
            const int b = m / FN;
            const int f = m - b * FN;
            src[i] = xb + (size_t)b * XLEN + (size_t)f * ST + e;
        } else {
            int n = n0 + (sec - 2) * 128 + row;
            if (n > CPAD - 1) n = CPAD - 1;    // rows 1026..1151 are zeros
            src[i] = wb + (size_t)n * KW + e;
        }
    }

    // ---- fragment read base offsets (bytes within one 64KB buffer) ----
    const int swz = (lm & 7) << 4;
    int abo[2], bbo[2];
#pragma unroll
    for (int ks = 0; ks < 2; ++ks) {
        abo[ks] = wr * 16384 + lm * 128 + ((ks * 64 + lq * 16) ^ swz);
        bbo[ks] = 32768 + (wc >> 1) * 16384 + ((wc & 1) * 64 + lm) * 128
                  + ((ks * 64 + lq * 16) ^ swz);
    }

    floatx4 acc[8][4];
#pragma unroll
    for (int i = 0; i < 8; ++i)
#pragma unroll
        for (int j = 0; j < 4; ++j) acc[i][j] = (floatx4)0.0f;

    // prologue: stage K-tile 0 into buf0
#pragma unroll
    for (int i = 0; i < 8; ++i) {
        load_lds16(src[i], lds + ldsq[i]);
        src[i] += C1_BK;
    }
    __syncthreads();

    for (int t = 0; t < C1_NT; ++t) {
        char* cur = lds + (t & 1) * C1_BUF;
        char* nxt = lds + ((t + 1) & 1) * C1_BUF;
        bf16x8 af[4][2], bf[2][2];

        // ===== phase 1: quadrant (mh=0, nh=0) =====
#pragma unroll
        for (int mt = 0; mt < 4; ++mt)
#pragma unroll
            for (int ks = 0; ks < 2; ++ks)
                af[mt][ks] = *(const bf16x8*)(cur + abo[ks] + mt * 2048);
#pragma unroll
        for (int nt = 0; nt < 2; ++nt)
#pragma unroll
            for (int ks = 0; ks < 2; ++ks)
                bf[nt][ks] = *(const bf16x8*)(cur + bbo[ks] + nt * 2048);
        if (t + 1 < C1_NT) {
#pragma unroll
            for (int i = 0; i < 8; ++i) {
                load_lds16(src[i], nxt + ldsq[i]);
                src[i] += C1_BK;
            }
        }
        __builtin_amdgcn_s_barrier();
        __builtin_amdgcn_s_setprio(1);
#pragma unroll
        for (int mt = 0; mt < 4; ++mt)
#pragma unroll
            for (int nt = 0; nt < 2; ++nt)
#pragma unroll
                for (int ks = 0; ks < 2; ++ks)
                    acc[mt][nt] = __builtin_amdgcn_mfma_f32_16x16x32_bf16(
                        af[mt][ks], bf[nt][ks], acc[mt][nt], 0, 0, 0);
        __builtin_amdgcn_s_setprio(0);
        __builtin_amdgcn_s_barrier();

        // ===== phase 2: quadrant (0,1) — keep A, read B(nh=1) =====
#pragma unroll
        for (int nt = 0; nt < 2; ++nt)
#pragma unroll
            for (int ks = 0; ks < 2; ++ks)
                bf[nt][ks] = *(const bf16x8*)(cur + bbo[ks] + (2 + nt) * 2048);
        __builtin_amdgcn_s_barrier();
        __builtin_amdgcn_s_setprio(1);
#pragma unroll
        for (int mt = 0; mt < 4; ++mt)
#pragma unroll
            for (int nt = 0; nt < 2; ++nt)
#pragma unroll
                for (int ks = 0; ks < 2; ++ks)
                    acc[mt][2 + nt] = __builtin_amdgcn_mfma_f32_16x16x32_bf16(
                        af[mt][ks], bf[nt][ks], acc[mt][2 + nt], 0, 0, 0);
        __builtin_amdgcn_s_setprio(0);
        __builtin_amdgcn_s_barrier();

        // ===== phase 3: quadrant (1,1) — keep B, read A(mh=1) =====
#pragma unroll
        for (int mt = 0; mt < 4; ++mt)
#pragma unroll
            for (int ks = 0; ks < 2; ++ks)
                af[mt][ks] = *(const bf16x8*)(cur + abo[ks] + (4 + mt) * 2048);
        __builtin_amdgcn_s_barrier();
        __builtin_amdgcn_s_setprio(1);
#pragma unroll
        for (int mt = 0; mt < 4; ++mt)
#pragma unroll
            for (int nt = 0; nt < 2; ++nt)
#pragma unroll
                for (int ks = 0; ks < 2; ++ks)
                    acc[4 + mt][2 + nt] = __builtin_amdgcn_mfma_f32_16x16x32_bf16(
                        af[mt][ks], bf[nt][ks], acc[4 + mt][2 + nt], 0, 0, 0);
        __builtin_amdgcn_s_setprio(0);
        __builtin_amdgcn_s_barrier();

        // ===== phase 4: quadrant (1,0) — keep A, re-read B(nh=0) =====
#pragma unroll
        for (int nt = 0; nt < 2; ++nt)
#pragma unroll
            for (int ks = 0; ks < 2; ++ks)
                bf[nt][ks] = *(const bf16x8*)(cur + bbo[ks] + nt * 2048);
        __builtin_amdgcn_s_barrier();
        __builtin_amdgcn_s_setprio(1);
#pragma unroll
        for (int mt = 0; mt < 4; ++mt)
#pragma unroll
            for (int nt = 0; nt < 2; ++nt)
#pragma unroll
                for (int ks = 0; ks < 2; ++ks)
                    acc[4 + mt][nt] = __builtin_amdgcn_mfma_f32_16x16x32_bf16(
                        af[mt][ks], bf[nt][ks], acc[4 + mt][nt], 0, 0, 0);
        __builtin_amdgcn_s_setprio(0);
        // tile boundary: drains vmcnt (loads issued 3 phases ago) + barrier
        __syncthreads();
    }

    // ---- epilogue ----
    float w1[16], b1v[8], w2[8];
#pragma unroll
    for (int o = 0; o < 8; ++o) {
        w1[2 * o]     = c1w[2 * o];
        w1[2 * o + 1] = c1w[2 * o + 1];
        b1v[o] = c1b[o];
        w2[o] = c2w[o];
    }
    const float b2v = c2b[0];
    const bool evenlane = ((lane & 1) == 0);

#pragma unroll
    for (int ni = 0; ni < 4; ++ni) {
        const int n = n0 + wc * 64 + ni * 16 + lm;
        const bool valid_c = (n < TCN);
        const float gv = valid_c ? gamma[permch(n)] : 0.0f;
        const int nbase = n & ~1;
        const int ybase = n >> 1;
        const bool store_c = (nbase < TBP);
#pragma unroll
        for (int mi = 0; mi < 8; ++mi) {
#pragma unroll
            for (int rp = 0; rp < 2; ++rp) {
                const int ra = rp * 2;
                const int mrow = m0 + wr * 128 + mi * 16 + lq * 4 + ra;
                const float ua = acc[mi][ni][ra] * gv;
                const float ub = acc[mi][ni][ra + 1] * gv;
                const float ta  = 2.0f / (1.0f + __expf(-2.0f * ua)) - 1.0f;
                const float tbv = 2.0f / (1.0f + __expf(-2.0f * ub)) - 1.0f;
                const float sa = __shfl_xor(ta, 1);
                const float sb = __shfl_xor(tbv, 1);
                // even lane owns row mrow (re=ta, im=sa);
                // odd lane owns row mrow+1 (re=sb, im=tbv)
                const int  fme = evenlane ? mrow : (mrow + 1);
                const float re = evenlane ? ta : sb;
                const float im = evenlane ? sa : tbv;
                if (fme < MROWS) {
                    const int b = fme / FN;
                    const int f = fme - b * FN;
                    if (store_c) {
                        const unsigned pr = (unsigned)f2bf(re) |
                                            ((unsigned)f2bf(im) << 16);
                        *(unsigned*)&tb2[(size_t)b * FLATB + (size_t)f * TBP + nbase] = pr;
                    }
                    if (valid_c) {
                        float a2 = b2v;
#pragma unroll
                        for (int o = 0; o < 8; ++o) {
                            const float a1 = fmaxf(
                                re * w1[2 * o] + im * w1[2 * o + 1] + b1v[o], 0.0f);
                            a2 += a1 * w2[o];
                        }
                        h[(size_t)fme * KPH + ybase] = f2bf(fmaxf(a2, 0.0f));
                    }
                }
            }
        }
    }
}

// ---------------------------------------------------------------------------
// k_maskm (MFMA): hh = H * Wlin^T; mask = sigmoid(2*(hh+b)*g);
// RMW: one aligned uint per (m,y) scales the (re,im) pair in tb2.
// ---------------------------------------------------------------------------
__global__ __launch_bounds__(256) void k_maskm(
    const unsigned short* __restrict__ h, const unsigned short* __restrict__ wlb,
    const float* __restrict__ linb, const float* __restrict__ fcg,
    unsigned* __restrict__ tbu)
{
    __shared__ __align__(16) unsigned short As[128 * 32];
    __shared__ __align__(16) unsigned short Bs[128 * 32];

    const int m0 = blockIdx.x * 128, n0 = blockIdx.y * 128;
    const int tid = threadIdx.x;

    const int s0 = tid, s1 = tid + 256;
    const int ar0 = s0 >> 2, aq0 = s0 & 3;
    const int ar1 = s1 >> 2, aq1 = s1 & 3;
    const unsigned short* ga0 = h + (size_t)(m0 + ar0) * KPH + aq0 * 8;
    const unsigned short* ga1 = h + (size_t)(m0 + ar1) * KPH + aq1 * 8;
    const unsigned short* gb0 = wlb + (size_t)(n0 + ar0) * KPH + aq0 * 8;
    const unsigned short* gb1 = wlb + (size_t)(n0 + ar1) * KPH + aq1 * 8;
    unsigned short* la0 = &As[s0 * 8];
    unsigned short* la1 = &As[s1 * 8];
    unsigned short* lb0 = &Bs[s0 * 8];
    unsigned short* lb1 = &Bs[s1 * 8];

    const int wave = tid >> 6, lane = tid & 63;
    const int lm = lane & 15, lq = lane >> 4;
    const int mw = (wave & 1) * 64, nw = (wave >> 1) * 64;
    const unsigned short* Ap = &As[(mw + lm) * 32 + lq * 8];
    const unsigned short* Bp = &Bs[(nw + lm) * 32 + lq * 8];

    floatx4 acc[4][4];
#pragma unroll
    for (int i = 0; i < 4; ++i)
#pragma unroll
        for (int j = 0; j < 4; ++j) acc[i][j] = (floatx4)0.0f;

    for (int ks = 0; ks < KPH / 32; ++ks) {
        load_lds16(ga0, la0);
        load_lds16(ga1, la1);
        load_lds16(gb0, lb0);
        load_lds16(gb1, lb1);
        ga0 += 32; ga1 += 32; gb0 += 32; gb1 += 32;
        __syncthreads();

        bf16x8 afr[4], bfr[4];
#pragma unroll
        for (int mt = 0; mt < 4; ++mt) afr[mt] = *(const bf16x8*)(Ap + mt * 16 * 32);
#pragma unroll
        for (int nt = 0; nt < 4; ++nt) bfr[nt] = *(const bf16x8*)(Bp + nt * 16 * 32);
#pragma unroll
        for (int mt = 0; mt < 4; ++mt)
#pragma unroll
            for (int nt = 0; nt < 4; ++nt)
                acc[mt][nt] = __builtin_amdgcn_mfma_f32_16x16x32_bf16(
                    afr[mt], bfr[nt], acc[mt][nt], 0, 0, 0);
        __syncthreads();
    }

#pragma unroll
    for (int nt = 0; nt < 4; ++nt) {
        const int y = n0 + nw + nt * 16 + lm;
        if (y < CUTN) {
            const float lb = linb[y];
            const float gv = fcg[y];
#pragma unroll
            for (int mt = 0; mt < 4; ++mt) {
#pragma unroll
                for (int r = 0; r < 4; ++r) {
                    const int m = m0 + mw + mt * 16 + lq * 4 + r;
                    if (m < MROWS) {
                        const float v = (acc[mt][nt][r] + lb) * gv;
                        const float msk = 1.0f / (1.0f + __expf(-2.0f * v));
                        unsigned* p = tbu + (size_t)m * (TBP / 2) + y;
                        const unsigned u = *p;
                        const float re = bf2f((unsigned short)(u & 0xffffu)) * msk;
                        const float im = bf2f((unsigned short)(u >> 16)) * msk;
                        *p = (unsigned)f2bf(re) | ((unsigned)f2bf(im) << 16);
                    }
                }
            }
        }
    }
}

// ---------------------------------------------------------------------------
// k_convtm (MFMA): d[m][r] = A(tb2 windows) * Wd^T, fused sigmoid softmax.
// ---------------------------------------------------------------------------
__global__ __launch_bounds__(256) void k_convtm(
    const unsigned short* __restrict__ tb2, const unsigned short* __restrict__ wdb,
    float* __restrict__ out)
{
    __shared__ __align__(16) unsigned short As[128 * 32];
    __shared__ __align__(16) unsigned short Bs[128 * 32];

    const int m0 = blockIdx.x * 128, n0 = blockIdx.y * 128;
    const int b   = m0 >> 10;
    const int ml0 = m0 & 1023;
    const int tid = threadIdx.x;

    const int s0 = tid, s1 = tid + 256;
    const int ar0 = s0 >> 2, aq0 = s0 & 3;
    const int ar1 = s1 >> 2, aq1 = s1 & 3;
    const unsigned short* tbb = tb2 + (size_t)b * FLATB;
    const unsigned short* ga0 = tbb + (size_t)(ml0 + ar0 + 1) * TBP + aq0 * 8;
    const unsigned short* ga1 = tbb + (size_t)(ml0 + ar1 + 1) * TBP + aq1 * 8;
    const unsigned short* gb0 = wdb + (size_t)(n0 + ar0) * KPC + aq0 * 8;
    const unsigned short* gb1 = wdb + (size_t)(n0 + ar1) * KPC + aq1 * 8;
    unsigned short* la0 = &As[s0 * 8];
    unsigned short* la1 = &As[s1 * 8];
    unsigned short* lb0 = &Bs[s0 * 8];
    unsigned short* lb1 = &Bs[s1 * 8];

    const int wave = tid >> 6, lane = tid & 63;
    const int lm = lane & 15, lq = lane >> 4;
    const int mw = (wave & 1) * 64, nw = (wave >> 1) * 64;
    const unsigned short* Ap = &As[(mw + lm) * 32 + lq * 8];
    const unsigned short* Bp = &Bs[(nw + lm) * 32 + lq * 8];

    floatx4 acc[4][4];
#pragma unroll
    for (int i = 0; i < 4; ++i)
#pragma unroll
        for (int j = 0; j < 4; ++j) acc[i][j] = (floatx4)0.0f;

    for (int ks = 0; ks < KPC / 32; ++ks) {
        load_lds16(ga0, la0);
        load_lds16(ga1, la1);
        load_lds16(gb0, lb0);
        load_lds16(gb1, lb1);
        ga0 += 32; ga1 += 32; gb0 += 32; gb1 += 32;
        __syncthreads();

        bf16x8 afr[4], bfr[4];
#pragma unroll
        for (int mt = 0; mt < 4; ++mt) afr[mt] = *(const bf16x8*)(Ap + mt * 16 * 32);
#pragma unroll
        for (int nt = 0; nt < 4; ++nt) bfr[nt] = *(const bf16x8*)(Bp + nt * 16 * 32);
#pragma unroll
        for (int mt = 0; mt < 4; ++mt)
#pragma unroll
            for (int nt = 0; nt < 4; ++nt)
                acc[mt][nt] = __builtin_amdgcn_mfma_f32_16x16x32_bf16(
                    afr[mt], bfr[nt], acc[mt][nt], 0, 0, 0);
        __syncthreads();
    }

    float* ob = out + (size_t)b * 2 * TIME_N;
#pragma unroll
    for (int nt = 0; nt < 4; ++nt) {
        const int n = n0 + nw + nt * 16 + lm;
#pragma unroll
        for (int mt = 0; mt < 4; ++mt) {
#pragma unroll
            for (int r = 0; r < 4; ++r) {
                const int m = ml0 + mw + mt * 16 + lq * 4 + r;
                const float d = acc[mt][nt][r];
                const float p0 = 1.0f / (1.0f + __expf(-d));
                const int tau = m * 256 + n;
                ob[tau]          = p0;
                ob[TIME_N + tau] = 1.0f - p0;
            }
        }
    }
}

extern "C" void kernel_launch(void* const* d_in, const int* in_sizes, int n_in,
                              void* d_out, int out_size, void* d_ws, size_t ws_size,
                              hipStream_t stream)
{
    const float* x    = (const float*)d_in[0];
    const float* c1w  = (const float*)d_in[1];
    const float* ing  = (const float*)d_in[2];
    const float* cb1w = (const float*)d_in[3];
    const float* cb1b = (const float*)d_in[4];
    const float* cb2w = (const float*)d_in[5];
    const float* cb2b = (const float*)d_in[6];
    const float* linw = (const float*)d_in[7];
    const float* linb = (const float*)d_in[8];
    const float* fcg  = (const float*)d_in[9];
    const float* ctw  = (const float*)d_in[10];
    float* out = (float*)d_out;

    // ---- workspace layout (all bf16) ----
    unsigned short* tb2 = (unsigned short*)d_ws;           // 32*1029*1032
    unsigned short* h   = tb2 + (size_t)BATCH * FLATB;     // 33024*544
    unsigned short* wlb = h + (size_t)MP * KPH;            // 640*544
    unsigned short* xb  = wlb + (size_t)NPH * KPH;         // 32*XLEN
    unsigned short* wbf = xb + (size_t)BATCH * XLEN;       // 1152*1024
    unsigned short* wdb = wbf + (size_t)CPAD * KW;         // 256*4128

    hipLaunchKernelGGL(k_prep, dim3(PB_TOTAL), dim3(256), 0, stream,
                       x, c1w, linw, ctw, xb, wbf, wlb, wdb);
    hipLaunchKernelGGL(k_conv1m, dim3(C1_MB, C1_NB), dim3(512), 2 * C1_BUF, stream,
                       xb, wbf, ing, cb1w, cb1b, cb2w, cb2b, tb2, h);
    hipLaunchKernelGGL(k_maskm, dim3(MP / 128, NPH / 128), dim3(256), 0, stream,
                       h, wlb, linb, fcg, (unsigned*)tb2);
    hipLaunchKernelGGL(k_convtm, dim3(256, 2), dim3(256), 0, stream,
                       tb2, wdb, out);
}

// Round 2
// 471.277 us; speedup vs baseline: 1.3355x; 1.3355x over previous
//
#include <hip/hip_runtime.h>
#include <cstddef>
#include <cstdint>

#define TIME_N 262144
#define BATCH  32
#define KW     1024
#define ST     256
#define CUTN   513
#define TCN    1026
#define FN     1029   // frames
#define FPAD   1152
#define CPAD   1152
#define XLEN   (FPAD * ST + KW)   // 295936 bf16 per batch row
#define XBLK   (XLEN / 256)       // 1156

// mask GEMM dims
#define MROWS  (BATCH * FN)   // 32928
#define MP     33024          // 258*128
#define KPH    544            // 513 -> 17*32
#define NPH    640            // 513 -> 5*128
// convT GEMM dims / flat bf16 t layout (re/im PAIR-INTERLEAVED: col 2y=re_y, 2y+1=im_y)
#define TBP    1040           // flat bf16 t row stride (16B-aligned, 65*16; K div by 64)
#define FLATB  (FN * TBP)     // per-batch flat size
#define KPC    4160           // 4*1040 = 65*64

// k_prep block ranges
#define PB_XPAD  (XBLK * BATCH)            // 36992
#define PB_WBF   (PB_XPAD + CPAD)          // +1152
#define PB_WLIN  (PB_WBF + NPH)            // +640
#define PB_TOTAL (PB_WLIN + KPC)           // +4160

typedef __bf16 bf16x8 __attribute__((ext_vector_type(8)));
typedef float floatx4 __attribute__((ext_vector_type(4)));

__device__ __forceinline__ unsigned short f2bf(float f) {
    union { float f; unsigned u; } v; v.f = f;
    unsigned r = (v.u + 0x7fffu + ((v.u >> 16) & 1u)) >> 16;
    return (unsigned short)r;
}
__device__ __forceinline__ float bf2f(unsigned short s) {
    union { unsigned u; float f; } v; v.u = ((unsigned)s) << 16;
    return v.f;
}
// interleaved column n -> original channel index
__device__ __forceinline__ int permch(int n) {
    return (n & 1) ? (CUTN + (n >> 1)) : (n >> 1);
}

__device__ __forceinline__ void load_lds16(const void* g, void* l) {
    __builtin_amdgcn_global_load_lds(
        (const __attribute__((address_space(1))) void*)g,
        (__attribute__((address_space(3))) void*)l, 16, 0, 0);
}

// ---------------------------------------------------------------------------
// k_prep: all input-conversion work in ONE launch, split by blockIdx range.
// ---------------------------------------------------------------------------
__global__ __launch_bounds__(256) void k_prep(
    const float* __restrict__ x, const float* __restrict__ c1w,
    const float* __restrict__ lw, const float* __restrict__ wct,
    unsigned short* __restrict__ xb, unsigned short* __restrict__ wbf,
    unsigned short* __restrict__ wlb, unsigned short* __restrict__ wdb)
{
    const int bid = blockIdx.x;
    if (bid < PB_XPAD) {
        const int b = bid / XBLK;
        const int p = (bid - b * XBLK) * 256 + threadIdx.x;
        const int g = p - KW;
        float v = (g >= 0 && g < TIME_N) ? x[(size_t)b * TIME_N + g] : 0.0f;
        xb[(size_t)b * XLEN + p] = f2bf(v);
    } else if (bid < PB_WBF) {
        const int n = bid - PB_XPAD;              // 0..1151 interleaved row
        const int ch = (n < TCN) ? permch(n) : 0;
        for (int k = threadIdx.x; k < KW; k += 256) {
            float v = (n < TCN) ? c1w[(size_t)ch * KW + k] : 0.0f;
            wbf[(size_t)n * KW + k] = f2bf(v);
        }
    } else if (bid < PB_WLIN) {
        const int n = bid - PB_WBF;               // 0..639
        for (int k = threadIdx.x; k < KPH; k += 256) {
            float v = (n < CUTN && k < CUTN) ? lw[(size_t)n * CUTN + k] : 0.0f;
            wlb[(size_t)n * KPH + k] = f2bf(v);
        }
    } else {
        const int k = bid - PB_WLIN;              // 0..4159
        const int r = threadIdx.x;                // 0..255
        const int j = k / TBP;
        const int n = k - j * TBP;
        float v = 0.0f;
        if (n < TCN) {
            const int ch = permch(n);
            const int widx = (3 - j) * 256 + r;
            v = wct[(size_t)(2 * ch) * KW + widx] -
                wct[(size_t)(2 * ch + 1) * KW + widx];
        }
        wdb[(size_t)r * KPC + k] = f2bf(v);
    }
}

// ---------------------------------------------------------------------------
// k_conv1m (MFMA): conv1 bf16 GEMM, 128x128 tile, BK=64 (16 K-steps instead
// of 32 -> half the barrier/drain stall points of the 2-phase structure).
// LDS XOR-swizzle byte^=((row&7)<<4), realized as pre-swizzled GLOBAL source
// addresses (global_load_lds dest stays linear) + swizzled ds_read addresses
// (verified correct in the round-1 kernel: bank conflicts 1.06e7 -> 0).
// Epilogue unchanged: tanh(gamma*.) -> pair-interleaved tb2 + h=MLP(re,im),
// both-lane scheme (even lane owns frame r, odd lane frame r+1).
// ---------------------------------------------------------------------------
__global__ __launch_bounds__(256) void k_conv1m(
    const unsigned short* __restrict__ xb, const unsigned short* __restrict__ wb,
    const float* __restrict__ gamma,
    const float* __restrict__ c1w, const float* __restrict__ c1b,
    const float* __restrict__ c2w, const float* __restrict__ c2b,
    unsigned short* __restrict__ tb2, unsigned short* __restrict__ h)
{
    __shared__ __align__(16) unsigned short As[128 * 64];
    __shared__ __align__(16) unsigned short Bs[128 * 64];

    const int b = blockIdx.x, fb = blockIdx.y, cb = blockIdx.z;
    const int f0 = fb * 128, c0 = cb * 128;
    const int tid = threadIdx.x;

    // staging: 1024 chunks of 16B per operand; 4 chunks/thread/operand
    const unsigned short* xrow = xb + (size_t)b * XLEN;
    const unsigned short* ga[4];
    const unsigned short* gb[4];
    int qa[4];
#pragma unroll
    for (int i = 0; i < 4; ++i) {
        const int c = i * 256 + tid;             // chunk 0..1023
        const int row = c >> 3;                  // 0..127
        const int colb = (c & 7) * 16;           // byte col in 128B row
        const int es = (colb ^ ((row & 7) << 4)) >> 1;   // inverse-swz element
        qa[i] = c * 16;                          // linear LDS byte offset
        ga[i] = xrow + (size_t)(f0 + row) * ST + es;
        gb[i] = wb + (size_t)(c0 + row) * KW + es;
    }

    const int wave = tid >> 6, lane = tid & 63;
    const int lm = lane & 15, lq = lane >> 4;
    const int mw = (wave & 1) * 64, nw = (wave >> 1) * 64;
    const int swz = (lm & 7) << 4;
    int abo[2], bbo[2];
#pragma unroll
    for (int ks = 0; ks < 2; ++ks) {
        abo[ks] = (mw + lm) * 128 + ((ks * 64 + lq * 16) ^ swz);
        bbo[ks] = (nw + lm) * 128 + ((ks * 64 + lq * 16) ^ swz);
    }

    floatx4 acc[4][4];
#pragma unroll
    for (int i = 0; i < 4; ++i)
#pragma unroll
        for (int j = 0; j < 4; ++j) acc[i][j] = (floatx4)0.0f;

    const char* Ab = (const char*)As;
    const char* Bb = (const char*)Bs;

    for (int t = 0; t < KW / 64; ++t) {
#pragma unroll
        for (int i = 0; i < 4; ++i) {
            load_lds16(ga[i], (char*)As + qa[i]);
            load_lds16(gb[i], (char*)Bs + qa[i]);
            ga[i] += 64; gb[i] += 64;
        }
        __syncthreads();

        bf16x8 afr[4][2], bfr[4][2];
#pragma unroll
        for (int mt = 0; mt < 4; ++mt)
#pragma unroll
            for (int ks = 0; ks < 2; ++ks)
                afr[mt][ks] = *(const bf16x8*)(Ab + abo[ks] + mt * 2048);
#pragma unroll
        for (int nt = 0; nt < 4; ++nt)
#pragma unroll
            for (int ks = 0; ks < 2; ++ks)
                bfr[nt][ks] = *(const bf16x8*)(Bb + bbo[ks] + nt * 2048);
#pragma unroll
        for (int mt = 0; mt < 4; ++mt)
#pragma unroll
            for (int nt = 0; nt < 4; ++nt)
#pragma unroll
                for (int ks = 0; ks < 2; ++ks)
                    acc[mt][nt] = __builtin_amdgcn_mfma_f32_16x16x32_bf16(
                        afr[mt][ks], bfr[nt][ks], acc[mt][nt], 0, 0, 0);
        __syncthreads();
    }

    // epilogue
    float w1[16], b1[8], w2[8];
#pragma unroll
    for (int o = 0; o < 8; ++o) {
        w1[2 * o]     = c1w[2 * o];
        w1[2 * o + 1] = c1w[2 * o + 1];
        b1[o] = c1b[o];
        w2[o] = c2w[o];
    }
    const float b2v = c2b[0];

    unsigned short* tbb = tb2 + (size_t)b * FLATB;
    const bool evenlane = ((lane & 1) == 0);
#pragma unroll
    for (int nt = 0; nt < 4; ++nt) {
        const int n = c0 + nw + nt * 16 + lm;
        const bool valid_c = (n < TCN);
        const float gv = valid_c ? gamma[permch(n)] : 0.0f;
        const int nbase = n & ~1;
        const int ybase = n >> 1;
        const bool store_c = (nbase < TBP);
#pragma unroll
        for (int mt = 0; mt < 4; ++mt) {
#pragma unroll
            for (int rp = 0; rp < 2; ++rp) {
                const int ra = rp * 2;
                const int fa = f0 + mw + mt * 16 + lq * 4 + ra;
                const float ua = acc[mt][nt][ra] * gv;
                const float ub = acc[mt][nt][ra + 1] * gv;
                const float ta  = 2.0f / (1.0f + __expf(-2.0f * ua)) - 1.0f;
                const float tbv = 2.0f / (1.0f + __expf(-2.0f * ub)) - 1.0f;
                const float sa = __shfl_xor(ta, 1);
                const float sb = __shfl_xor(tbv, 1);
                // even lane owns frame fa with (re=ta, im=sa);
                // odd lane owns frame fa+1 with (re=sb, im=tbv)
                const int  fme = evenlane ? fa : (fa + 1);
                const float re = evenlane ? ta : sb;
                const float im = evenlane ? sa : tbv;
                if (fme < FN) {
                    if (store_c) {
                        const unsigned pr = (unsigned)f2bf(re) |
                                            ((unsigned)f2bf(im) << 16);
                        *(unsigned*)&tbb[(size_t)fme * TBP + nbase] = pr;
                    }
                    if (valid_c) {
                        float a2 = b2v;
#pragma unroll
                        for (int o = 0; o < 8; ++o) {
                            const float a1 = fmaxf(
                                re * w1[2 * o] + im * w1[2 * o + 1] + b1[o], 0.0f);
                            a2 += a1 * w2[o];
                        }
                        h[((size_t)b * FN + fme) * KPH + ybase] =
                            f2bf(fmaxf(a2, 0.0f));
                    }
                }
            }
        }
    }
}

// ---------------------------------------------------------------------------
// k_maskm (MFMA): hh = H * Wlin^T; mask = sigmoid(2*(hh+b)*g);
// RMW: one aligned uint per (m,y) scales the (re,im) pair in tb2.
// (unchanged from the 512us baseline; KPH=544 is not divisible by 64)
// ---------------------------------------------------------------------------
__global__ __launch_bounds__(256) void k_maskm(
    const unsigned short* __restrict__ h, const unsigned short* __restrict__ wlb,
    const float* __restrict__ linb, const float* __restrict__ fcg,
    unsigned* __restrict__ tbu)
{
    __shared__ __align__(16) unsigned short As[128 * 32];
    __shared__ __align__(16) unsigned short Bs[128 * 32];

    const int m0 = blockIdx.x * 128, n0 = blockIdx.y * 128;
    const int tid = threadIdx.x;

    const int s0 = tid, s1 = tid + 256;
    const int ar0 = s0 >> 2, aq0 = s0 & 3;
    const int ar1 = s1 >> 2, aq1 = s1 & 3;
    const unsigned short* ga0 = h + (size_t)(m0 + ar0) * KPH + aq0 * 8;
    const unsigned short* ga1 = h + (size_t)(m0 + ar1) * KPH + aq1 * 8;
    const unsigned short* gb0 = wlb + (size_t)(n0 + ar0) * KPH + aq0 * 8;
    const unsigned short* gb1 = wlb + (size_t)(n0 + ar1) * KPH + aq1 * 8;
    unsigned short* la0 = &As[s0 * 8];
    unsigned short* la1 = &As[s1 * 8];
    unsigned short* lb0 = &Bs[s0 * 8];
    unsigned short* lb1 = &Bs[s1 * 8];

    const int wave = tid >> 6, lane = tid & 63;
    const int lm = lane & 15, lq = lane >> 4;
    const int mw = (wave & 1) * 64, nw = (wave >> 1) * 64;
    const unsigned short* Ap = &As[(mw + lm) * 32 + lq * 8];
    const unsigned short* Bp = &Bs[(nw + lm) * 32 + lq * 8];

    floatx4 acc[4][4];
#pragma unroll
    for (int i = 0; i < 4; ++i)
#pragma unroll
        for (int j = 0; j < 4; ++j) acc[i][j] = (floatx4)0.0f;

    for (int ks = 0; ks < KPH / 32; ++ks) {
        load_lds16(ga0, la0);
        load_lds16(ga1, la1);
        load_lds16(gb0, lb0);
        load_lds16(gb1, lb1);
        ga0 += 32; ga1 += 32; gb0 += 32; gb1 += 32;
        __syncthreads();

        bf16x8 afr[4], bfr[4];
#pragma unroll
        for (int mt = 0; mt < 4; ++mt) afr[mt] = *(const bf16x8*)(Ap + mt * 16 * 32);
#pragma unroll
        for (int nt = 0; nt < 4; ++nt) bfr[nt] = *(const bf16x8*)(Bp + nt * 16 * 32);
#pragma unroll
        for (int mt = 0; mt < 4; ++mt)
#pragma unroll
            for (int nt = 0; nt < 4; ++nt)
                acc[mt][nt] = __builtin_amdgcn_mfma_f32_16x16x32_bf16(
                    afr[mt], bfr[nt], acc[mt][nt], 0, 0, 0);
        __syncthreads();
    }

#pragma unroll
    for (int nt = 0; nt < 4; ++nt) {
        const int y = n0 + nw + nt * 16 + lm;
        if (y < CUTN) {
            const float lb = linb[y];
            const float gv = fcg[y];
#pragma unroll
            for (int mt = 0; mt < 4; ++mt) {
#pragma unroll
                for (int r = 0; r < 4; ++r) {
                    const int m = m0 + mw + mt * 16 + lq * 4 + r;
                    if (m < MROWS) {
                        const float v = (acc[mt][nt][r] + lb) * gv;
                        const float msk = 1.0f / (1.0f + __expf(-2.0f * v));
                        unsigned* p = tbu + (size_t)m * (TBP / 2) + y;
                        const unsigned u = *p;
                        const float re = bf2f((unsigned short)(u & 0xffffu)) * msk;
                        const float im = bf2f((unsigned short)(u >> 16)) * msk;
                        *p = (unsigned)f2bf(re) | ((unsigned)f2bf(im) << 16);
                    }
                }
            }
        }
    }
}

// ---------------------------------------------------------------------------
// k_convtm (MFMA): d[m][r] = A(tb2 windows) * Wd^T, fused sigmoid softmax.
// BK=64 (65 K-steps instead of 129), same XOR-swizzle machinery as k_conv1m.
// ---------------------------------------------------------------------------
__global__ __launch_bounds__(256) void k_convtm(
    const unsigned short* __restrict__ tb2, const unsigned short* __restrict__ wdb,
    float* __restrict__ out)
{
    __shared__ __align__(16) unsigned short As[128 * 64];
    __shared__ __align__(16) unsigned short Bs[128 * 64];

    const int m0 = blockIdx.x * 128, n0 = blockIdx.y * 128;
    const int b   = m0 >> 10;
    const int ml0 = m0 & 1023;
    const int tid = threadIdx.x;

    const unsigned short* tbb = tb2 + (size_t)b * FLATB;
    const unsigned short* ga[4];
    const unsigned short* gb[4];
    int qa[4];
#pragma unroll
    for (int i = 0; i < 4; ++i) {
        const int c = i * 256 + tid;             // chunk 0..1023
        const int row = c >> 3;                  // 0..127
        const int colb = (c & 7) * 16;
        const int es = (colb ^ ((row & 7) << 4)) >> 1;
        qa[i] = c * 16;
        ga[i] = tbb + (size_t)(ml0 + row + 1) * TBP + es;
        gb[i] = wdb + (size_t)(n0 + row) * KPC + es;
    }

    const int wave = tid >> 6, lane = tid & 63;
    const int lm = lane & 15, lq = lane >> 4;
    const int mw = (wave & 1) * 64, nw = (wave >> 1) * 64;
    const int swz = (lm & 7) << 4;
    int abo[2], bbo[2];
#pragma unroll
    for (int ks = 0; ks < 2; ++ks) {
        abo[ks] = (mw + lm) * 128 + ((ks * 64 + lq * 16) ^ swz);
        bbo[ks] = (nw + lm) * 128 + ((ks * 64 + lq * 16) ^ swz);
    }

    floatx4 acc[4][4];
#pragma unroll
    for (int i = 0; i < 4; ++i)
#pragma unroll
        for (int j = 0; j < 4; ++j) acc[i][j] = (floatx4)0.0f;

    const char* Ab = (const char*)As;
    const char* Bb = (const char*)Bs;

    for (int t = 0; t < KPC / 64; ++t) {
#pragma unroll
        for (int i = 0; i < 4; ++i) {
            load_lds16(ga[i], (char*)As + qa[i]);
            load_lds16(gb[i], (char*)Bs + qa[i]);
            ga[i] += 64; gb[i] += 64;
        }
        __syncthreads();

        bf16x8 afr[4][2], bfr[4][2];
#pragma unroll
        for (int mt = 0; mt < 4; ++mt)
#pragma unroll
            for (int ks = 0; ks < 2; ++ks)
                afr[mt][ks] = *(const bf16x8*)(Ab + abo[ks] + mt * 2048);
#pragma unroll
        for (int nt = 0; nt < 4; ++nt)
#pragma unroll
            for (int ks = 0; ks < 2; ++ks)
                bfr[nt][ks] = *(const bf16x8*)(Bb + bbo[ks] + nt * 2048);
#pragma unroll
        for (int mt = 0; mt < 4; ++mt)
#pragma unroll
            for (int nt = 0; nt < 4; ++nt)
#pragma unroll
                for (int ks = 0; ks < 2; ++ks)
                    acc[mt][nt] = __builtin_amdgcn_mfma_f32_16x16x32_bf16(
                        afr[mt][ks], bfr[nt][ks], acc[mt][nt], 0, 0, 0);
        __syncthreads();
    }

    float* ob = out + (size_t)b * 2 * TIME_N;
#pragma unroll
    for (int nt = 0; nt < 4; ++nt) {
        const int n = n0 + nw + nt * 16 + lm;
#pragma unroll
        for (int mt = 0; mt < 4; ++mt) {
#pragma unroll
            for (int r = 0; r < 4; ++r) {
                const int m = ml0 + mw + mt * 16 + lq * 4 + r;
                const float d = acc[mt][nt][r];
                const float p0 = 1.0f / (1.0f + __expf(-d));
                const int tau = m * 256 + n;
                ob[tau]          = p0;
                ob[TIME_N + tau] = 1.0f - p0;
            }
        }
    }
}

extern "C" void kernel_launch(void* const* d_in, const int* in_sizes, int n_in,
                              void* d_out, int out_size, void* d_ws, size_t ws_size,
                              hipStream_t stream)
{
    const float* x    = (const float*)d_in[0];
    const float* c1w  = (const float*)d_in[1];
    const float* ing  = (const float*)d_in[2];
    const float* cb1w = (const float*)d_in[3];
    const float* cb1b = (const float*)d_in[4];
    const float* cb2w = (const float*)d_in[5];
    const float* cb2b = (const float*)d_in[6];
    const float* linw = (const float*)d_in[7];
    const float* linb = (const float*)d_in[8];
    const float* fcg  = (const float*)d_in[9];
    const float* ctw  = (const float*)d_in[10];
    float* out = (float*)d_out;

    // ---- workspace layout (all bf16) ----
    unsigned short* tb2 = (unsigned short*)d_ws;           // 32*1029*1040
    unsigned short* h   = tb2 + (size_t)BATCH * FLATB;     // 33024*544
    unsigned short* wlb = h + (size_t)MP * KPH;            // 640*544
    unsigned short* xb  = wlb + (size_t)NPH * KPH;         // 32*XLEN
    unsigned short* wbf = xb + (size_t)BATCH * XLEN;       // 1152*1024
    unsigned short* wdb = wbf + (size_t)CPAD * KW;         // 256*4160

    hipLaunchKernelGGL(k_prep, dim3(PB_TOTAL), dim3(256), 0, stream,
                       x, c1w, linw, ctw, xb, wbf, wlb, wdb);
    hipLaunchKernelGGL(k_conv1m, dim3(BATCH, 9, 9), dim3(256), 0, stream,
                       xb, wbf, ing, cb1w, cb1b, cb2w, cb2b, tb2, h);
    hipLaunchKernelGGL(k_maskm, dim3(MP / 128, NPH / 128), dim3(256), 0, stream,
                       h, wlb, linb, fcg, (unsigned*)tb2);
    hipLaunchKernelGGL(k_convtm, dim3(256, 2), dim3(256), 0, stream,
                       tb2, wdb, out);
}

// Round 4
// 446.349 us; speedup vs baseline: 1.4101x; 1.0558x over previous
//
#include <hip/hip_runtime.h>
#include <cstddef>
#include <cstdint>

#define TIME_N 262144
#define BATCH  32
#define KW     1024
#define ST     256
#define CUTN   513
#define TCN    1026
#define FN     1029   // frames
#define FPAD   1152
#define CPAD   1152
#define XLEN   (FPAD * ST + KW)   // 295936 bf16 per batch row
#define XBLK   (XLEN / 256)       // 1156

// mask GEMM dims
#define MROWS  (BATCH * FN)   // 32928
#define MP     33024          // 258*128
#define KPH    544            // 513 -> 17*32
#define NPH    640            // 513 -> 5*128
// convT GEMM dims / flat bf16 t layout (re/im PAIR-INTERLEAVED: col 2y=re_y, 2y+1=im_y)
#define TBP    1040           // flat bf16 t row stride (16B-aligned, 65*16; K div by 64)
#define FLATB  (FN * TBP)     // per-batch flat size
#define KPC    4160           // 4*1040 = 65*64

// k_prep block ranges
#define PB_XPAD  (XBLK * BATCH)            // 36992
#define PB_WBF   (PB_XPAD + CPAD)          // +1152
#define PB_WLIN  (PB_WBF + NPH)            // +640
#define PB_TOTAL (PB_WLIN + KPC)           // +4160

typedef __bf16 bf16x8 __attribute__((ext_vector_type(8)));
typedef float floatx4 __attribute__((ext_vector_type(4)));

__device__ __forceinline__ unsigned short f2bf(float f) {
    union { float f; unsigned u; } v; v.f = f;
    unsigned r = (v.u + 0x7fffu + ((v.u >> 16) & 1u)) >> 16;
    return (unsigned short)r;
}
__device__ __forceinline__ float bf2f(unsigned short s) {
    union { unsigned u; float f; } v; v.u = ((unsigned)s) << 16;
    return v.f;
}
// interleaved column n -> original channel index
__device__ __forceinline__ int permch(int n) {
    return (n & 1) ? (CUTN + (n >> 1)) : (n >> 1);
}

__device__ __forceinline__ void load_lds16(const void* g, void* l) {
    __builtin_amdgcn_global_load_lds(
        (const __attribute__((address_space(1))) void*)g,
        (__attribute__((address_space(3))) void*)l, 16, 0, 0);
}

// ---------------------------------------------------------------------------
// k_prep: all input-conversion work in ONE launch, split by blockIdx range.
// ---------------------------------------------------------------------------
__global__ __launch_bounds__(256) void k_prep(
    const float* __restrict__ x, const float* __restrict__ c1w,
    const float* __restrict__ lw, const float* __restrict__ wct,
    unsigned short* __restrict__ xb, unsigned short* __restrict__ wbf,
    unsigned short* __restrict__ wlb, unsigned short* __restrict__ wdb)
{
    const int bid = blockIdx.x;
    if (bid < PB_XPAD) {
        const int b = bid / XBLK;
        const int p = (bid - b * XBLK) * 256 + threadIdx.x;
        const int g = p - KW;
        float v = (g >= 0 && g < TIME_N) ? x[(size_t)b * TIME_N + g] : 0.0f;
        xb[(size_t)b * XLEN + p] = f2bf(v);
    } else if (bid < PB_WBF) {
        const int n = bid - PB_XPAD;              // 0..1151 interleaved row
        const int ch = (n < TCN) ? permch(n) : 0;
        for (int k = threadIdx.x; k < KW; k += 256) {
            float v = (n < TCN) ? c1w[(size_t)ch * KW + k] : 0.0f;
            wbf[(size_t)n * KW + k] = f2bf(v);
        }
    } else if (bid < PB_WLIN) {
        const int n = bid - PB_WBF;               // 0..639
        for (int k = threadIdx.x; k < KPH; k += 256) {
            float v = (n < CUTN && k < CUTN) ? lw[(size_t)n * CUTN + k] : 0.0f;
            wlb[(size_t)n * KPH + k] = f2bf(v);
        }
    } else {
        const int k = bid - PB_WLIN;              // 0..4159
        const int r = threadIdx.x;                // 0..255
        const int j = k / TBP;
        const int n = k - j * TBP;
        float v = 0.0f;
        if (n < TCN) {
            const int ch = permch(n);
            const int widx = (3 - j) * 256 + r;
            v = wct[(size_t)(2 * ch) * KW + widx] -
                wct[(size_t)(2 * ch + 1) * KW + widx];
        }
        wdb[(size_t)r * KPC + k] = f2bf(v);
    }
}

// ---------------------------------------------------------------------------
// k_conv1m (MFMA): conv1 bf16 GEMM, 128x128 tile, BK=64, DOUBLE-BUFFERED LDS
// with the T3-minimum pipeline (m248 recipe): issue next tile's
// global_load_lds into buf^1 BEFORE computing the current tile; ONE
// __syncthreads per K-step (its implicit vmcnt(0) drains loads issued a full
// iteration earlier -> latency covered, not exposed).
// LDS XOR-swizzle byte^=((row&7)<<4) via pre-swizzled global source +
// swizzled ds_read addresses (verified: bank conflicts 1.06e7 -> 0).
// Epilogue unchanged: tanh(gamma*.) -> pair-interleaved tb2 + h=MLP(re,im).
// ---------------------------------------------------------------------------
__global__ __launch_bounds__(256) void k_conv1m(
    const unsigned short* __restrict__ xb, const unsigned short* __restrict__ wb,
    const float* __restrict__ gamma,
    const float* __restrict__ c1w, const float* __restrict__ c1b,
    const float* __restrict__ c2w, const float* __restrict__ c2b,
    unsigned short* __restrict__ tb2, unsigned short* __restrict__ h)
{
    extern __shared__ __align__(16) char lds[];   // 2 x (A 16KB + B 16KB) = 64KB

    const int b = blockIdx.x, fb = blockIdx.y, cb = blockIdx.z;
    const int f0 = fb * 128, c0 = cb * 128;
    const int tid = threadIdx.x;

    // staging: 1024 chunks of 16B per operand; 4 chunks/thread/operand
    const unsigned short* xrow = xb + (size_t)b * XLEN;
    const unsigned short* ga[4];
    const unsigned short* gb[4];
    int qa[4];
#pragma unroll
    for (int i = 0; i < 4; ++i) {
        const int c = i * 256 + tid;             // chunk 0..1023
        const int row = c >> 3;                  // 0..127
        const int colb = (c & 7) * 16;           // byte col in 128B row
        const int es = (colb ^ ((row & 7) << 4)) >> 1;   // inverse-swz element
        qa[i] = c * 16;                          // linear LDS byte offset
        ga[i] = xrow + (size_t)(f0 + row) * ST + es;
        gb[i] = wb + (size_t)(c0 + row) * KW + es;
    }

    const int wave = tid >> 6, lane = tid & 63;
    const int lm = lane & 15, lq = lane >> 4;
    const int mw = (wave & 1) * 64, nw = (wave >> 1) * 64;
    const int swz = (lm & 7) << 4;
    int abo[2], bbo[2];
#pragma unroll
    for (int ks = 0; ks < 2; ++ks) {
        abo[ks] = (mw + lm) * 128 + ((ks * 64 + lq * 16) ^ swz);
        bbo[ks] = 16384 + (nw + lm) * 128 + ((ks * 64 + lq * 16) ^ swz);
    }

    floatx4 acc[4][4];
#pragma unroll
    for (int i = 0; i < 4; ++i)
#pragma unroll
        for (int j = 0; j < 4; ++j) acc[i][j] = (floatx4)0.0f;

    // prologue: stage K-tile 0 into buf 0
#pragma unroll
    for (int i = 0; i < 4; ++i) {
        load_lds16(ga[i], lds + qa[i]);
        load_lds16(gb[i], lds + 16384 + qa[i]);
        ga[i] += 64; gb[i] += 64;
    }
    __syncthreads();

    for (int t = 0; t < KW / 64; ++t) {
        char* cur = lds + (t & 1) * 32768;
        char* nxt = lds + ((t + 1) & 1) * 32768;

        // issue next tile's stage FIRST (T3-minimum: loads in flight across
        // the compute phase; drained by the barrier below)
        if (t + 1 < KW / 64) {
#pragma unroll
            for (int i = 0; i < 4; ++i) {
                load_lds16(ga[i], nxt + qa[i]);
                load_lds16(gb[i], nxt + 16384 + qa[i]);
                ga[i] += 64; gb[i] += 64;
            }
        }

        bf16x8 afr[4][2], bfr[4][2];
#pragma unroll
        for (int mt = 0; mt < 4; ++mt)
#pragma unroll
            for (int ks = 0; ks < 2; ++ks)
                afr[mt][ks] = *(const bf16x8*)(cur + abo[ks] + mt * 2048);
#pragma unroll
        for (int nt = 0; nt < 4; ++nt)
#pragma unroll
            for (int ks = 0; ks < 2; ++ks)
                bfr[nt][ks] = *(const bf16x8*)(cur + bbo[ks] + nt * 2048);
#pragma unroll
        for (int mt = 0; mt < 4; ++mt)
#pragma unroll
            for (int nt = 0; nt < 4; ++nt)
#pragma unroll
                for (int ks = 0; ks < 2; ++ks)
                    acc[mt][nt] = __builtin_amdgcn_mfma_f32_16x16x32_bf16(
                        afr[mt][ks], bfr[nt][ks], acc[mt][nt], 0, 0, 0);
        // one barrier per K-step: drains vmcnt (issued above, covered by the
        // ds_read+MFMA phase) and releases cur for overwrite at t+2
        __syncthreads();
    }

    // epilogue
    float w1[16], b1[8], w2[8];
#pragma unroll
    for (int o = 0; o < 8; ++o) {
        w1[2 * o]     = c1w[2 * o];
        w1[2 * o + 1] = c1w[2 * o + 1];
        b1[o] = c1b[o];
        w2[o] = c2w[o];
    }
    const float b2v = c2b[0];

    unsigned short* tbb = tb2 + (size_t)b * FLATB;
    const bool evenlane = ((lane & 1) == 0);
#pragma unroll
    for (int nt = 0; nt < 4; ++nt) {
        const int n = c0 + nw + nt * 16 + lm;
        const bool valid_c = (n < TCN);
        const float gv = valid_c ? gamma[permch(n)] : 0.0f;
        const int nbase = n & ~1;
        const int ybase = n >> 1;
        const bool store_c = (nbase < TBP);
#pragma unroll
        for (int mt = 0; mt < 4; ++mt) {
#pragma unroll
            for (int rp = 0; rp < 2; ++rp) {
                const int ra = rp * 2;
                const int fa = f0 + mw + mt * 16 + lq * 4 + ra;
                const float ua = acc[mt][nt][ra] * gv;
                const float ub = acc[mt][nt][ra + 1] * gv;
                const float ta  = 2.0f / (1.0f + __expf(-2.0f * ua)) - 1.0f;
                const float tbv = 2.0f / (1.0f + __expf(-2.0f * ub)) - 1.0f;
                const float sa = __shfl_xor(ta, 1);
                const float sb = __shfl_xor(tbv, 1);
                // even lane owns frame fa with (re=ta, im=sa);
                // odd lane owns frame fa+1 with (re=sb, im=tbv)
                const int  fme = evenlane ? fa : (fa + 1);
                const float re = evenlane ? ta : sb;
                const float im = evenlane ? sa : tbv;
                if (fme < FN) {
                    if (store_c) {
                        const unsigned pr = (unsigned)f2bf(re) |
                                            ((unsigned)f2bf(im) << 16);
                        *(unsigned*)&tbb[(size_t)fme * TBP + nbase] = pr;
                    }
                    if (valid_c) {
                        float a2 = b2v;
#pragma unroll
                        for (int o = 0; o < 8; ++o) {
                            const float a1 = fmaxf(
                                re * w1[2 * o] + im * w1[2 * o + 1] + b1[o], 0.0f);
                            a2 += a1 * w2[o];
                        }
                        h[((size_t)b * FN + fme) * KPH + ybase] =
                            f2bf(fmaxf(a2, 0.0f));
                    }
                }
            }
        }
    }
}

// ---------------------------------------------------------------------------
// k_maskm (MFMA): hh = H * Wlin^T; mask = sigmoid(2*(hh+b)*g);
// RMW: one aligned uint per (m,y) scales the (re,im) pair in tb2.
// (unchanged; KPH=544 is not divisible by 64)
// ---------------------------------------------------------------------------
__global__ __launch_bounds__(256) void k_maskm(
    const unsigned short* __restrict__ h, const unsigned short* __restrict__ wlb,
    const float* __restrict__ linb, const float* __restrict__ fcg,
    unsigned* __restrict__ tbu)
{
    __shared__ __align__(16) unsigned short As[128 * 32];
    __shared__ __align__(16) unsigned short Bs[128 * 32];

    const int m0 = blockIdx.x * 128, n0 = blockIdx.y * 128;
    const int tid = threadIdx.x;

    const int s0 = tid, s1 = tid + 256;
    const int ar0 = s0 >> 2, aq0 = s0 & 3;
    const int ar1 = s1 >> 2, aq1 = s1 & 3;
    const unsigned short* ga0 = h + (size_t)(m0 + ar0) * KPH + aq0 * 8;
    const unsigned short* ga1 = h + (size_t)(m0 + ar1) * KPH + aq1 * 8;
    const unsigned short* gb0 = wlb + (size_t)(n0 + ar0) * KPH + aq0 * 8;
    const unsigned short* gb1 = wlb + (size_t)(n0 + ar1) * KPH + aq1 * 8;
    unsigned short* la0 = &As[s0 * 8];
    unsigned short* la1 = &As[s1 * 8];
    unsigned short* lb0 = &Bs[s0 * 8];
    unsigned short* lb1 = &Bs[s1 * 8];

    const int wave = tid >> 6, lane = tid & 63;
    const int lm = lane & 15, lq = lane >> 4;
    const int mw = (wave & 1) * 64, nw = (wave >> 1) * 64;
    const unsigned short* Ap = &As[(mw + lm) * 32 + lq * 8];
    const unsigned short* Bp = &Bs[(nw + lm) * 32 + lq * 8];

    floatx4 acc[4][4];
#pragma unroll
    for (int i = 0; i < 4; ++i)
#pragma unroll
        for (int j = 0; j < 4; ++j) acc[i][j] = (floatx4)0.0f;

    for (int ks = 0; ks < KPH / 32; ++ks) {
        load_lds16(ga0, la0);
        load_lds16(ga1, la1);
        load_lds16(gb0, lb0);
        load_lds16(gb1, lb1);
        ga0 += 32; ga1 += 32; gb0 += 32; gb1 += 32;
        __syncthreads();

        bf16x8 afr[4], bfr[4];
#pragma unroll
        for (int mt = 0; mt < 4; ++mt) afr[mt] = *(const bf16x8*)(Ap + mt * 16 * 32);
#pragma unroll
        for (int nt = 0; nt < 4; ++nt) bfr[nt] = *(const bf16x8*)(Bp + nt * 16 * 32);
#pragma unroll
        for (int mt = 0; mt < 4; ++mt)
#pragma unroll
            for (int nt = 0; nt < 4; ++nt)
                acc[mt][nt] = __builtin_amdgcn_mfma_f32_16x16x32_bf16(
                    afr[mt], bfr[nt], acc[mt][nt], 0, 0, 0);
        __syncthreads();
    }

#pragma unroll
    for (int nt = 0; nt < 4; ++nt) {
        const int y = n0 + nw + nt * 16 + lm;
        if (y < CUTN) {
            const float lb = linb[y];
            const float gv = fcg[y];
#pragma unroll
            for (int mt = 0; mt < 4; ++mt) {
#pragma unroll
                for (int r = 0; r < 4; ++r) {
                    const int m = m0 + mw + mt * 16 + lq * 4 + r;
                    if (m < MROWS) {
                        const float v = (acc[mt][nt][r] + lb) * gv;
                        const float msk = 1.0f / (1.0f + __expf(-2.0f * v));
                        unsigned* p = tbu + (size_t)m * (TBP / 2) + y;
                        const unsigned u = *p;
                        const float re = bf2f((unsigned short)(u & 0xffffu)) * msk;
                        const float im = bf2f((unsigned short)(u >> 16)) * msk;
                        *p = (unsigned)f2bf(re) | ((unsigned)f2bf(im) << 16);
                    }
                }
            }
        }
    }
}

// ---------------------------------------------------------------------------
// k_convtm (MFMA): d[m][r] = A(tb2 windows) * Wd^T, fused sigmoid softmax.
// BK=64, double-buffered with the same T3-minimum pipeline as k_conv1m
// (65-step K-loop amortizes the prologue well).
// ---------------------------------------------------------------------------
__global__ __launch_bounds__(256) void k_convtm(
    const unsigned short* __restrict__ tb2, const unsigned short* __restrict__ wdb,
    float* __restrict__ out)
{
    extern __shared__ __align__(16) char lds[];   // 2 x 32KB

    const int m0 = blockIdx.x * 128, n0 = blockIdx.y * 128;
    const int b   = m0 >> 10;
    const int ml0 = m0 & 1023;
    const int tid = threadIdx.x;

    const unsigned short* tbb = tb2 + (size_t)b * FLATB;
    const unsigned short* ga[4];
    const unsigned short* gb[4];
    int qa[4];
#pragma unroll
    for (int i = 0; i < 4; ++i) {
        const int c = i * 256 + tid;             // chunk 0..1023
        const int row = c >> 3;                  // 0..127
        const int colb = (c & 7) * 16;
        const int es = (colb ^ ((row & 7) << 4)) >> 1;
        qa[i] = c * 16;
        ga[i] = tbb + (size_t)(ml0 + row + 1) * TBP + es;
        gb[i] = wdb + (size_t)(n0 + row) * KPC + es;
    }

    const int wave = tid >> 6, lane = tid & 63;
    const int lm = lane & 15, lq = lane >> 4;
    const int mw = (wave & 1) * 64, nw = (wave >> 1) * 64;
    const int swz = (lm & 7) << 4;
    int abo[2], bbo[2];
#pragma unroll
    for (int ks = 0; ks < 2; ++ks) {
        abo[ks] = (mw + lm) * 128 + ((ks * 64 + lq * 16) ^ swz);
        bbo[ks] = 16384 + (nw + lm) * 128 + ((ks * 64 + lq * 16) ^ swz);
    }

    floatx4 acc[4][4];
#pragma unroll
    for (int i = 0; i < 4; ++i)
#pragma unroll
        for (int j = 0; j < 4; ++j) acc[i][j] = (floatx4)0.0f;

    // prologue: stage K-tile 0 into buf 0
#pragma unroll
    for (int i = 0; i < 4; ++i) {
        load_lds16(ga[i], lds + qa[i]);
        load_lds16(gb[i], lds + 16384 + qa[i]);
        ga[i] += 64; gb[i] += 64;
    }
    __syncthreads();

    for (int t = 0; t < KPC / 64; ++t) {
        char* cur = lds + (t & 1) * 32768;
        char* nxt = lds + ((t + 1) & 1) * 32768;

        if (t + 1 < KPC / 64) {
#pragma unroll
            for (int i = 0; i < 4; ++i) {
                load_lds16(ga[i], nxt + qa[i]);
                load_lds16(gb[i], nxt + 16384 + qa[i]);
                ga[i] += 64; gb[i] += 64;
            }
        }

        bf16x8 afr[4][2], bfr[4][2];
#pragma unroll
        for (int mt = 0; mt < 4; ++mt)
#pragma unroll
            for (int ks = 0; ks < 2; ++ks)
                afr[mt][ks] = *(const bf16x8*)(cur + abo[ks] + mt * 2048);
#pragma unroll
        for (int nt = 0; nt < 4; ++nt)
#pragma unroll
            for (int ks = 0; ks < 2; ++ks)
                bfr[nt][ks] = *(const bf16x8*)(cur + bbo[ks] + nt * 2048);
#pragma unroll
        for (int mt = 0; mt < 4; ++mt)
#pragma unroll
            for (int nt = 0; nt < 4; ++nt)
#pragma unroll
                for (int ks = 0; ks < 2; ++ks)
                    acc[mt][nt] = __builtin_amdgcn_mfma_f32_16x16x32_bf16(
                        afr[mt][ks], bfr[nt][ks], acc[mt][nt], 0, 0, 0);
        __syncthreads();
    }

    float* ob = out + (size_t)b * 2 * TIME_N;
#pragma unroll
    for (int nt = 0; nt < 4; ++nt) {
        const int n = n0 + nw + nt * 16 + lm;
#pragma unroll
        for (int mt = 0; mt < 4; ++mt) {
#pragma unroll
            for (int r = 0; r < 4; ++r) {
                const int m = ml0 + mw + mt * 16 + lq * 4 + r;
                const float d = acc[mt][nt][r];
                const float p0 = 1.0f / (1.0f + __expf(-d));
                const int tau = m * 256 + n;
                ob[tau]          = p0;
                ob[TIME_N + tau] = 1.0f - p0;
            }
        }
    }
}

extern "C" void kernel_launch(void* const* d_in, const int* in_sizes, int n_in,
                              void* d_out, int out_size, void* d_ws, size_t ws_size,
                              hipStream_t stream)
{
    const float* x    = (const float*)d_in[0];
    const float* c1w  = (const float*)d_in[1];
    const float* ing  = (const float*)d_in[2];
    const float* cb1w = (const float*)d_in[3];
    const float* cb1b = (const float*)d_in[4];
    const float* cb2w = (const float*)d_in[5];
    const float* cb2b = (const float*)d_in[6];
    const float* linw = (const float*)d_in[7];
    const float* linb = (const float*)d_in[8];
    const float* fcg  = (const float*)d_in[9];
    const float* ctw  = (const float*)d_in[10];
    float* out = (float*)d_out;

    // ---- workspace layout (all bf16) ----
    unsigned short* tb2 = (unsigned short*)d_ws;           // 32*1029*1040
    unsigned short* h   = tb2 + (size_t)BATCH * FLATB;     // 33024*544
    unsigned short* wlb = h + (size_t)MP * KPH;            // 640*544
    unsigned short* xb  = wlb + (size_t)NPH * KPH;         // 32*XLEN
    unsigned short* wbf = xb + (size_t)BATCH * XLEN;       // 1152*1024
    unsigned short* wdb = wbf + (size_t)CPAD * KW;         // 256*4160

    hipLaunchKernelGGL(k_prep, dim3(PB_TOTAL), dim3(256), 0, stream,
                       x, c1w, linw, ctw, xb, wbf, wlb, wdb);
    hipLaunchKernelGGL(k_conv1m, dim3(BATCH, 9, 9), dim3(256), 65536, stream,
                       xb, wbf, ing, cb1w, cb1b, cb2w, cb2b, tb2, h);
    hipLaunchKernelGGL(k_maskm, dim3(MP / 128, NPH / 128), dim3(256), 0, stream,
                       h, wlb, linb, fcg, (unsigned*)tb2);
    hipLaunchKernelGGL(k_convtm, dim3(256, 2), dim3(256), 65536, stream,
                       tb2, wdb, out);
}